// Round 1
// baseline (244.156 us; speedup 1.0000x reference)
//
#include <hip/hip_runtime.h>

#define N_NODES 50000
#define N_EDGES 800000
#define F_IN 256
#define H1 8
#define N_HID 256
#define N_CLASS 47
#define MAXDEG 48
#define NW16 (N_NODES/16)   // 3125 16-row tiles

typedef __attribute__((ext_vector_type(8))) __bf16 bf16x8;
typedef __attribute__((ext_vector_type(4))) float f32x4;

__device__ __forceinline__ float bf2f(unsigned short u){
    union { unsigned int i; float f; } c; c.i = ((unsigned int)u) << 16; return c.f;
}
__device__ __forceinline__ float bf2f_lo(unsigned int u){
    union { unsigned int i; float f; } c; c.i = u << 16; return c.f;
}
__device__ __forceinline__ float bf2f_hi(unsigned int u){
    union { unsigned int i; float f; } c; c.i = u & 0xffff0000u; return c.f;
}
__device__ __forceinline__ unsigned short f2b(float f){
    union { float f; unsigned int i; } c; c.f = f;
    unsigned int u = c.i;
    unsigned int r = u + 0x7FFFu + ((u >> 16) & 1u);
    return (unsigned short)(r >> 16);
}

// ---- prologue: zero cnt + pack W1/W2 B-frags + pack [Wl1|Wr1] B-frag ----
// B frag (16x16x32): lane holds B[k][n], n = lane&15, k = (lane>>4)*8 + j
__global__ void k_pre(const float* __restrict__ W1,
                      const float* __restrict__ W2,
                      const float* __restrict__ Wl1,
                      const float* __restrict__ Wr1,
                      int* __restrict__ cnt,
                      unsigned short* __restrict__ bp1,
                      unsigned short* __restrict__ bp2,
                      unsigned short* __restrict__ bp3){
    int tid = blockIdx.x * blockDim.x + threadIdx.x;
    if (tid < N_NODES) cnt[tid] = 0;
    if (tid < 8*2*64*8) {                       // 8192: W1, 2 col-tiles
        int j = tid & 7, lane = (tid >> 3) & 63, tile = (tid >> 9) & 1, kc = tid >> 10;
        int k = kc*32 + (lane >> 4)*8 + j;
        int n = tile*16 + (lane & 15);
        bp1[tid] = f2b(W1[k*32 + n]);
    }
    int t2 = tid - 8192;
    if (t2 >= 0 && t2 < 8*3*64*8) {             // 12288: W2, 3 col-tiles (pad 48)
        int j = t2 & 7, lane = (t2 >> 3) & 63;
        int tile = (t2 >> 9) % 3, kc = t2 / 1536;
        int k = kc*32 + (lane >> 4)*8 + j;
        int n = tile*16 + (lane & 15);
        bp2[t2] = (n < N_CLASS) ? f2b(W2[k*N_CLASS + n]) : (unsigned short)0;
    }
    int t3 = tid - 20480;
    if (t3 >= 0 && t3 < 512) {                  // [Wl1|Wr1]: K=32, N=16 (8 el + 8 er)
        int j = t3 & 7, lane = t3 >> 3;
        int n = lane & 15, k = (lane >> 4)*8 + j;
        bp3[t3] = (n < 8) ? f2b(Wl1[k*8 + n]) : f2b(Wr1[k*8 + (n - 8)]);
    }
}

// ---- padded-CSR build (uint16 ids): one atomic per edge ----
__global__ void k_fill(const int* __restrict__ src, const int* __restrict__ dst,
                       int* __restrict__ cnt, unsigned short* __restrict__ csrp){
    int e = blockIdx.x * blockDim.x + threadIdx.x;
    if (e < N_EDGES){
        int s = src[e];
        s = ((unsigned)s < N_NODES) ? s : 0;
        int p = atomicAdd(&cnt[s], 1);
        if (p < MAXDEG) csrp[(size_t)s*MAXDEG + p] = (unsigned short)dst[e];
    }
}

// ---- GEMM1 + fused elr1: h1 = x@W1 (MFMA); el1/er1 = h1@[Wl1|Wr1] (MFMA) ----
// h1-tile round-trips per-wave LDS (C-layout -> A-frag layout, stride 40).
__global__ __launch_bounds__(256)
void k_gemm1(const float* __restrict__ x,
             const unsigned short* __restrict__ bp1,
             const unsigned short* __restrict__ bp3,
             unsigned short* __restrict__ h1b,
             float* __restrict__ el1, float* __restrict__ er1){
    __shared__ __align__(16) unsigned short lds_h[4][16][40];
    int w = threadIdx.x >> 6;
    int wid = (blockIdx.x * blockDim.x + threadIdx.x) >> 6;
    int lane = threadIdx.x & 63;
    if (wid >= NW16) return;
    int m0 = wid * 16;
    int mrow = m0 + (lane & 15);
    int q = lane >> 4;
    f32x4 z = {0.f,0.f,0.f,0.f};
    f32x4 acc0 = z, acc1 = z;
    const float* xrow = x + (size_t)mrow * F_IN + q * 8;
    #pragma unroll
    for (int kc = 0; kc < 8; kc++){
        const f32x4* xp = (const f32x4*)(xrow + kc*32);
        f32x4 u0 = xp[0], u1 = xp[1];
        union { bf16x8 v; unsigned short s[8]; } ua;
        ua.s[0]=f2b(u0[0]); ua.s[1]=f2b(u0[1]); ua.s[2]=f2b(u0[2]); ua.s[3]=f2b(u0[3]);
        ua.s[4]=f2b(u1[0]); ua.s[5]=f2b(u1[1]); ua.s[6]=f2b(u1[2]); ua.s[7]=f2b(u1[3]);
        bf16x8 b0 = *reinterpret_cast<const bf16x8*>(bp1 + kc*1024 + lane*8);
        bf16x8 b1 = *reinterpret_cast<const bf16x8*>(bp1 + kc*1024 + 512 + lane*8);
        acc0 = __builtin_amdgcn_mfma_f32_16x16x32_bf16(ua.v, b0, acc0, 0, 0, 0);
        acc1 = __builtin_amdgcn_mfma_f32_16x16x32_bf16(ua.v, b1, acc1, 0, 0, 0);
    }
    int col = lane & 15, rbase = q * 4;
    #pragma unroll
    for (int r = 0; r < 4; r++){
        int row = m0 + rbase + r;
        unsigned short v0 = f2b(acc0[r]), v1 = f2b(acc1[r]);
        h1b[(size_t)row*32 + col]      = v0;
        h1b[(size_t)row*32 + 16 + col] = v1;
        lds_h[w][rbase + r][col]      = v0;   // wave-local transpose staging
        lds_h[w][rbase + r][16 + col] = v1;
    }
    // within-wave LDS: ds ops are wave-ordered; compiler inserts lgkmcnt wait
    bf16x8 a2 = *reinterpret_cast<const bf16x8*>(&lds_h[w][lane & 15][q*8]);
    bf16x8 b3 = *reinterpret_cast<const bf16x8*>(bp3 + lane*8);
    f32x4 e = z;
    e = __builtin_amdgcn_mfma_f32_16x16x32_bf16(a2, b3, e, 0, 0, 0);
    #pragma unroll
    for (int r = 0; r < 4; r++){
        int row = m0 + rbase + r;
        if (col < 8) el1[(size_t)row*8 + col]     = e[r];
        else         er1[(size_t)row*8 + col - 8] = e[r];
    }
}

// ---- fused: agg1 (+ELU) for 16 nodes -> LDS -> GEMM2 -> h2 + fused elr2 ----
// lane = (head = lane>>3, featquad = lane&7). All 4 nodes' edge ids / el1 /
// cnt prefetched up front; edge loop unrolled x8 (16 gathers in flight).
__global__ __launch_bounds__(256)
void k_agg1g2(const unsigned short* __restrict__ h1b,
              const float* __restrict__ el1, const float* __restrict__ er1,
              const float* __restrict__ b1,
              const float* __restrict__ Wl2, const float* __restrict__ Wr2,
              const int* __restrict__ cnt, const unsigned short* __restrict__ csrp,
              const unsigned short* __restrict__ bp2,
              unsigned short* __restrict__ h2b,
              float* __restrict__ el2, float* __restrict__ er2){
    __shared__ __align__(16) unsigned short lds_r[16][264];
    __shared__ float lds_p[2][3][16];
    int w = threadIdx.x >> 6, lane = threadIdx.x & 63;
    int h = lane >> 3, fq = lane & 7, fb = fq * 4;
    int base = blockIdx.x * 16;
    int node0 = base + w * 4;
    int4 n4 = *(const int4*)(cnt + node0);            // 16B-aligned
    int n_[4] = { min(n4.x, MAXDEG), min(n4.y, MAXDEG),
                  min(n4.z, MAXDEG), min(n4.w, MAXDEG) };
    int dl[4];                                        // prefetch edge ids, 4 nodes
    #pragma unroll
    for (int i = 0; i < 4; i++){
        const unsigned short* lst = csrp + (size_t)(node0 + i) * MAXDEG;
        int dd = (lane < MAXDEG) ? (int)lst[lane] : 0;
        dl[i] = (dd < N_NODES) ? dd : 0;
    }
    float elh[4];
    #pragma unroll
    for (int i = 0; i < 4; i++) elh[i] = el1[(node0 + i)*8 + h];
    float bv0 = b1[fb], bv1 = b1[fb+1], bv2 = b1[fb+2], bv3 = b1[fb+3];
    #pragma unroll
    for (int i = 0; i < 4; i++){
        int n = n_[i];
        float el_h = elh[i];
        float a0=0.f, a1=0.f, a2=0.f, a3=0.f, ds=0.f;
        for (int e = 0; e < n; e += 8){
            int d0 = __shfl(dl[i], e);
            int d1 = __shfl(dl[i], e+1);
            int d2 = __shfl(dl[i], e+2);
            int d3 = __shfl(dl[i], e+3);
            int d4 = __shfl(dl[i], e+4);
            int d5 = __shfl(dl[i], e+5);
            int d6 = __shfl(dl[i], e+6);
            int d7 = __shfl(dl[i], e+7);
            uint2 hp0 = *(const uint2*)(h1b + (size_t)d0*32 + fb);
            uint2 hp1 = *(const uint2*)(h1b + (size_t)d1*32 + fb);
            uint2 hp2 = *(const uint2*)(h1b + (size_t)d2*32 + fb);
            uint2 hp3 = *(const uint2*)(h1b + (size_t)d3*32 + fb);
            uint2 hp4 = *(const uint2*)(h1b + (size_t)d4*32 + fb);
            uint2 hp5 = *(const uint2*)(h1b + (size_t)d5*32 + fb);
            uint2 hp6 = *(const uint2*)(h1b + (size_t)d6*32 + fb);
            uint2 hp7 = *(const uint2*)(h1b + (size_t)d7*32 + fb);
            float e0 = er1[d0*8 + h], e1 = er1[d1*8 + h];
            float e2 = er1[d2*8 + h], e3 = er1[d3*8 + h];
            float e4 = er1[d4*8 + h], e5 = er1[d5*8 + h];
            float e6 = er1[d6*8 + h], e7 = er1[d7*8 + h];
            float t0 = el_h+e0; t0 = (t0>0.f)?t0:0.2f*t0;
            float t1 = el_h+e1; t1 = (t1>0.f)?t1:0.2f*t1;
            float t2 = el_h+e2; t2 = (t2>0.f)?t2:0.2f*t2;
            float t3 = el_h+e3; t3 = (t3>0.f)?t3:0.2f*t3;
            float t4 = el_h+e4; t4 = (t4>0.f)?t4:0.2f*t4;
            float t5 = el_h+e5; t5 = (t5>0.f)?t5:0.2f*t5;
            float t6 = el_h+e6; t6 = (t6>0.f)?t6:0.2f*t6;
            float t7 = el_h+e7; t7 = (t7>0.f)?t7:0.2f*t7;
            float w0 = __expf(fminf(t0,60.f));
            float w1 = __expf(fminf(t1,60.f)); w1 = (e+1<n)?w1:0.f;
            float w2 = __expf(fminf(t2,60.f)); w2 = (e+2<n)?w2:0.f;
            float w3 = __expf(fminf(t3,60.f)); w3 = (e+3<n)?w3:0.f;
            float w4 = __expf(fminf(t4,60.f)); w4 = (e+4<n)?w4:0.f;
            float w5 = __expf(fminf(t5,60.f)); w5 = (e+5<n)?w5:0.f;
            float w6 = __expf(fminf(t6,60.f)); w6 = (e+6<n)?w6:0.f;
            float w7 = __expf(fminf(t7,60.f)); w7 = (e+7<n)?w7:0.f;
            ds += ((w0+w1)+(w2+w3)) + ((w4+w5)+(w6+w7));
            a0 += w0*bf2f_lo(hp0.x) + w1*bf2f_lo(hp1.x) + w2*bf2f_lo(hp2.x) + w3*bf2f_lo(hp3.x)
                + w4*bf2f_lo(hp4.x) + w5*bf2f_lo(hp5.x) + w6*bf2f_lo(hp6.x) + w7*bf2f_lo(hp7.x);
            a1 += w0*bf2f_hi(hp0.x) + w1*bf2f_hi(hp1.x) + w2*bf2f_hi(hp2.x) + w3*bf2f_hi(hp3.x)
                + w4*bf2f_hi(hp4.x) + w5*bf2f_hi(hp5.x) + w6*bf2f_hi(hp6.x) + w7*bf2f_hi(hp7.x);
            a2 += w0*bf2f_lo(hp0.y) + w1*bf2f_lo(hp1.y) + w2*bf2f_lo(hp2.y) + w3*bf2f_lo(hp3.y)
                + w4*bf2f_lo(hp4.y) + w5*bf2f_lo(hp5.y) + w6*bf2f_lo(hp6.y) + w7*bf2f_lo(hp7.y);
            a3 += w0*bf2f_hi(hp0.y) + w1*bf2f_hi(hp1.y) + w2*bf2f_hi(hp2.y) + w3*bf2f_hi(hp3.y)
                + w4*bf2f_hi(hp4.y) + w5*bf2f_hi(hp5.y) + w6*bf2f_hi(hp6.y) + w7*bf2f_hi(hp7.y);
        }
        float inv = 1.f / fmaxf(ds, 1e-12f);
        float o0 = a0*inv + bv0, o1 = a1*inv + bv1, o2 = a2*inv + bv2, o3 = a3*inv + bv3;
        o0 = (o0 > 0.f) ? o0 : (__expf(o0) - 1.f);
        o1 = (o1 > 0.f) ? o1 : (__expf(o1) - 1.f);
        o2 = (o2 > 0.f) ? o2 : (__expf(o2) - 1.f);
        o3 = (o3 > 0.f) ? o3 : (__expf(o3) - 1.f);
        unsigned int lo = (unsigned int)f2b(o0) | ((unsigned int)f2b(o1) << 16);
        unsigned int hi = (unsigned int)f2b(o2) | ((unsigned int)f2b(o3) << 16);
        *(uint2*)&lds_r[w*4 + i][h*32 + fb] = make_uint2(lo, hi);
    }
    __syncthreads();
    if (w < 3){
        int q = lane >> 4, m = lane & 15;
        f32x4 accd = {0.f,0.f,0.f,0.f};
        #pragma unroll
        for (int kc = 0; kc < 8; kc++){
            bf16x8 a = *reinterpret_cast<const bf16x8*>(&lds_r[m][kc*32 + q*8]);
            bf16x8 b = *reinterpret_cast<const bf16x8*>(bp2 + kc*1536 + w*512 + lane*8);
            accd = __builtin_amdgcn_mfma_f32_16x16x32_bf16(a, b, accd, 0, 0, 0);
        }
        int col = lane & 15, rbase = q * 4;
        int cls = w*16 + col;
        float wl2v = (cls < N_CLASS) ? Wl2[cls] : 0.f;
        float wr2v = (cls < N_CLASS) ? Wr2[cls] : 0.f;
        float pe[4], pr[4];
        #pragma unroll
        for (int r = 0; r < 4; r++){
            int grow = base + rbase + r;
            h2b[(size_t)grow*48 + w*16 + col] = f2b(accd[r]);
            pe[r] = accd[r] * wl2v;
            pr[r] = accd[r] * wr2v;
        }
        #pragma unroll
        for (int msk = 1; msk <= 8; msk <<= 1){
            #pragma unroll
            for (int r = 0; r < 4; r++){
                pe[r] += __shfl_xor(pe[r], msk);
                pr[r] += __shfl_xor(pr[r], msk);
            }
        }
        if (col == 0){
            #pragma unroll
            for (int r = 0; r < 4; r++){
                lds_p[0][w][rbase + r] = pe[r];
                lds_p[1][w][rbase + r] = pr[r];
            }
        }
    }
    __syncthreads();
    if (w == 3 && lane < 16){
        float ev = lds_p[0][0][lane] + lds_p[0][1][lane] + lds_p[0][2][lane];
        float rv = lds_p[1][0][lane] + lds_p[1][1][lane] + lds_p[1][2][lane];
        el2[base + lane] = ev;
        er2[base + lane] = rv;
    }
}

// ---- layer-2 aggregation + bias + log_softmax: wave per node, unroll x8 ----
__global__ __launch_bounds__(256)
void k_agg2(const unsigned short* __restrict__ h2b,
            const float* __restrict__ el2, const float* __restrict__ er2,
            const float* __restrict__ b2,
            const int* __restrict__ cnt, const unsigned short* __restrict__ csrp,
            float* __restrict__ out){
    int wid = (blockIdx.x * blockDim.x + threadIdx.x) >> 6;
    if (wid >= N_NODES) return;
    int lane = threadIdx.x & 63;
    int n = min(cnt[wid], MAXDEG);
    const unsigned short* lst = csrp + (size_t)wid * MAXDEG;
    float el_i = el2[wid];
    int   d_l = 0;
    float w_l = 0.f;
    if (lane < n){
        int dd = (int)lst[lane];
        d_l = (dd < N_NODES) ? dd : 0;
        float t = el_i + er2[d_l];
        t = (t > 0.f) ? t : 0.2f * t;
        w_l = __expf(fminf(t, 60.f));
    }
    float ds = w_l;
    #pragma unroll
    for (int m = 32; m >= 1; m >>= 1) ds += __shfl_xor(ds, m);
    bool valid = lane < N_CLASS;
    int cl = valid ? lane : 0;
    float acc0=0.f, acc1=0.f, acc2=0.f, acc3=0.f;
    for (int e = 0; e < n; e += 8){
        float we0 = __shfl(w_l, e);   int de0 = __shfl(d_l, e);
        float we1 = __shfl(w_l, e+1); int de1 = __shfl(d_l, e+1);
        float we2 = __shfl(w_l, e+2); int de2 = __shfl(d_l, e+2);
        float we3 = __shfl(w_l, e+3); int de3 = __shfl(d_l, e+3);
        float we4 = __shfl(w_l, e+4); int de4 = __shfl(d_l, e+4);
        float we5 = __shfl(w_l, e+5); int de5 = __shfl(d_l, e+5);
        float we6 = __shfl(w_l, e+6); int de6 = __shfl(d_l, e+6);
        float we7 = __shfl(w_l, e+7); int de7 = __shfl(d_l, e+7);
        acc0 += we0 * bf2f(h2b[(size_t)de0*48 + cl]);
        acc1 += we1 * bf2f(h2b[(size_t)de1*48 + cl]);
        acc2 += we2 * bf2f(h2b[(size_t)de2*48 + cl]);
        acc3 += we3 * bf2f(h2b[(size_t)de3*48 + cl]);
        acc0 += we4 * bf2f(h2b[(size_t)de4*48 + cl]);
        acc1 += we5 * bf2f(h2b[(size_t)de5*48 + cl]);
        acc2 += we6 * bf2f(h2b[(size_t)de6*48 + cl]);
        acc3 += we7 * bf2f(h2b[(size_t)de7*48 + cl]);
    }
    float acc = (acc0 + acc1) + (acc2 + acc3);
    float o = acc / fmaxf(ds, 1e-12f) + b2[cl];
    float zm = valid ? o : -1e30f;
    #pragma unroll
    for (int m = 32; m >= 1; m >>= 1) zm = fmaxf(zm, __shfl_xor(zm, m));
    float ex = valid ? __expf(fminf(o - zm, 0.f)) : 0.f;
    #pragma unroll
    for (int m = 32; m >= 1; m >>= 1) ex += __shfl_xor(ex, m);
    float res = o - zm - __logf(ex);
    if (valid) out[(size_t)wid*N_CLASS + lane] = res;
}

extern "C" void kernel_launch(void* const* d_in, const int* in_sizes, int n_in,
                              void* d_out, int out_size, void* d_ws, size_t ws_size,
                              hipStream_t stream){
    const float* x   = (const float*)d_in[0];
    const int*   esrc= (const int*)d_in[1];
    const int*   edst= (const int*)d_in[2];
    const float* W1  = (const float*)d_in[3];
    const float* Wl1 = (const float*)d_in[4];
    const float* Wr1 = (const float*)d_in[5];
    const float* b1  = (const float*)d_in[6];
    const float* W2  = (const float*)d_in[7];
    const float* Wl2 = (const float*)d_in[8];
    const float* Wr2 = (const float*)d_in[9];
    const float* b2  = (const float*)d_in[10];
    float* out = (float*)d_out;

    char* w = (char*)d_ws;
    auto carve = [&](size_t bytes) -> char* {
        char* p = w; w += (bytes + 255) & ~(size_t)255; return p;
    };
    int*            cnt  = (int*)            carve((size_t)N_NODES * 4);
    unsigned short* csrp = (unsigned short*) carve((size_t)N_NODES * MAXDEG * 2);
    unsigned short* h1b  = (unsigned short*) carve((size_t)N_NODES * 32 * 2);
    float*          el1  = (float*)          carve((size_t)N_NODES * 8 * 4);
    float*          er1  = (float*)          carve((size_t)N_NODES * 8 * 4);
    unsigned short* h2b  = (unsigned short*) carve((size_t)N_NODES * 48 * 2);
    float*          el2  = (float*)          carve((size_t)N_NODES * 4);
    float*          er2  = (float*)          carve((size_t)N_NODES * 4);
    unsigned short* bp1  = (unsigned short*) carve(8192 * 2);
    unsigned short* bp2  = (unsigned short*) carve(12288 * 2);
    unsigned short* bp3  = (unsigned short*) carve(512 * 2);

    k_pre    <<<(N_NODES + 255) / 256, 256, 0, stream>>>(W1, W2, Wl1, Wr1, cnt, bp1, bp2, bp3);
    k_fill   <<<(N_EDGES + 255) / 256, 256, 0, stream>>>(esrc, edst, cnt, csrp);
    k_gemm1  <<<(NW16 + 3) / 4, 256, 0, stream>>>(x, bp1, bp3, h1b, el1, er1);
    k_agg1g2 <<<NW16, 256, 0, stream>>>(h1b, el1, er1, b1, Wl2, Wr2, cnt, csrp, bp2, h2b, el2, er2);
    k_agg2   <<<(N_NODES + 3) / 4, 256, 0, stream>>>(h2b, el2, er2, b2, cnt, csrp, out);
}

// Round 2
// 224.843 us; speedup vs baseline: 1.0859x; 1.0859x over previous
//
#include <hip/hip_runtime.h>

#define N_NODES 50000
#define N_EDGES 800000
#define F_IN 256
#define H1 8
#define N_HID 256
#define N_CLASS 47
#define MAXDEG 48
#define NW16 (N_NODES/16)   // 3125 16-row tiles
#define G1BLK ((NW16 + 3) / 4)  // 782 gemm1 blocks in fused kernel

typedef __attribute__((ext_vector_type(8))) __bf16 bf16x8;
typedef __attribute__((ext_vector_type(4))) float f32x4;

__device__ __forceinline__ float bf2f(unsigned short u){
    union { unsigned int i; float f; } c; c.i = ((unsigned int)u) << 16; return c.f;
}
__device__ __forceinline__ unsigned short f2b(float f){
    union { float f; unsigned int i; } c; c.f = f;
    unsigned int u = c.i;
    unsigned int r = u + 0x7FFFu + ((u >> 16) & 1u);
    return (unsigned short)(r >> 16);
}

// ---- prologue: zero cnt + pack W1/W2 B-frags + pack [Wl1|Wr1] B-frag ----
// B frag (16x16x32): lane holds B[k][n], n = lane&15, k = (lane>>4)*8 + j
__global__ void k_pre(const float* __restrict__ W1,
                      const float* __restrict__ W2,
                      const float* __restrict__ Wl1,
                      const float* __restrict__ Wr1,
                      int* __restrict__ cnt,
                      unsigned short* __restrict__ bp1,
                      unsigned short* __restrict__ bp2,
                      unsigned short* __restrict__ bp3){
    int tid = blockIdx.x * blockDim.x + threadIdx.x;
    if (tid < N_NODES) cnt[tid] = 0;
    if (tid < 8*2*64*8) {                       // 8192: W1, 2 col-tiles
        int j = tid & 7, lane = (tid >> 3) & 63, tile = (tid >> 9) & 1, kc = tid >> 10;
        int k = kc*32 + (lane >> 4)*8 + j;
        int n = tile*16 + (lane & 15);
        bp1[tid] = f2b(W1[k*32 + n]);
    }
    int t2 = tid - 8192;
    if (t2 >= 0 && t2 < 8*3*64*8) {             // 12288: W2, 3 col-tiles (pad 48)
        int j = t2 & 7, lane = (t2 >> 3) & 63;
        int tile = (t2 >> 9) % 3, kc = t2 / 1536;
        int k = kc*32 + (lane >> 4)*8 + j;
        int n = tile*16 + (lane & 15);
        bp2[t2] = (n < N_CLASS) ? f2b(W2[k*N_CLASS + n]) : (unsigned short)0;
    }
    int t3 = tid - 20480;
    if (t3 >= 0 && t3 < 512) {                  // [Wl1|Wr1]: K=32, N=16 (8 el + 8 er)
        int j = t3 & 7, lane = t3 >> 3;
        int n = lane & 15, k = (lane >> 4)*8 + j;
        bp3[t3] = (n < 8) ? f2b(Wl1[k*8 + n]) : f2b(Wr1[k*8 + (n - 8)]);
    }
}

// ---- fused: GEMM1 (+elr1) blocks [0, G1BLK) ; CSR-fill blocks [G1BLK, ...) ----
// The two parts touch disjoint buffers; fusing overlaps their execution.
__global__ __launch_bounds__(256)
void k_fg(const float* __restrict__ x,
          const unsigned short* __restrict__ bp1,
          const unsigned short* __restrict__ bp3,
          unsigned short* __restrict__ h1b,
          float* __restrict__ el1, float* __restrict__ er1,
          const int* __restrict__ src, const int* __restrict__ dst,
          int* __restrict__ cnt, unsigned short* __restrict__ csrp){
    __shared__ __align__(16) unsigned short lds_h[4][16][40];
    if (blockIdx.x >= G1BLK){
        int e = (blockIdx.x - G1BLK) * blockDim.x + threadIdx.x;
        if (e < N_EDGES){
            int s = src[e];
            s = ((unsigned)s < N_NODES) ? s : 0;
            int p = atomicAdd(&cnt[s], 1);
            if (p < MAXDEG) csrp[(size_t)s*MAXDEG + p] = (unsigned short)dst[e];
        }
        return;
    }
    int w = threadIdx.x >> 6;
    int wid = (blockIdx.x * blockDim.x + threadIdx.x) >> 6;
    int lane = threadIdx.x & 63;
    if (wid >= NW16) return;
    int m0 = wid * 16;
    int mrow = m0 + (lane & 15);
    int q = lane >> 4;
    f32x4 z = {0.f,0.f,0.f,0.f};
    f32x4 acc0 = z, acc1 = z;
    const float* xrow = x + (size_t)mrow * F_IN + q * 8;
    #pragma unroll
    for (int kc = 0; kc < 8; kc++){
        const f32x4* xp = (const f32x4*)(xrow + kc*32);
        f32x4 u0 = xp[0], u1 = xp[1];
        union { bf16x8 v; unsigned short s[8]; } ua;
        ua.s[0]=f2b(u0[0]); ua.s[1]=f2b(u0[1]); ua.s[2]=f2b(u0[2]); ua.s[3]=f2b(u0[3]);
        ua.s[4]=f2b(u1[0]); ua.s[5]=f2b(u1[1]); ua.s[6]=f2b(u1[2]); ua.s[7]=f2b(u1[3]);
        bf16x8 b0 = *reinterpret_cast<const bf16x8*>(bp1 + kc*1024 + lane*8);
        bf16x8 b1 = *reinterpret_cast<const bf16x8*>(bp1 + kc*1024 + 512 + lane*8);
        acc0 = __builtin_amdgcn_mfma_f32_16x16x32_bf16(ua.v, b0, acc0, 0, 0, 0);
        acc1 = __builtin_amdgcn_mfma_f32_16x16x32_bf16(ua.v, b1, acc1, 0, 0, 0);
    }
    int col = lane & 15, rbase = q * 4;
    #pragma unroll
    for (int r = 0; r < 4; r++){
        int row = m0 + rbase + r;
        unsigned short v0 = f2b(acc0[r]), v1 = f2b(acc1[r]);
        h1b[(size_t)row*32 + col]      = v0;
        h1b[(size_t)row*32 + 16 + col] = v1;
        lds_h[w][rbase + r][col]      = v0;   // wave-local transpose staging
        lds_h[w][rbase + r][16 + col] = v1;
    }
    // within-wave LDS: ds ops are wave-ordered; compiler inserts lgkmcnt wait
    bf16x8 a2 = *reinterpret_cast<const bf16x8*>(&lds_h[w][lane & 15][q*8]);
    bf16x8 b3 = *reinterpret_cast<const bf16x8*>(bp3 + lane*8);
    f32x4 e = z;
    e = __builtin_amdgcn_mfma_f32_16x16x32_bf16(a2, b3, e, 0, 0, 0);
    #pragma unroll
    for (int r = 0; r < 4; r++){
        int row = m0 + rbase + r;
        if (col < 8) el1[(size_t)row*8 + col]     = e[r];
        else         er1[(size_t)row*8 + col - 8] = e[r];
    }
}

// ---- fused: agg1 via MFMA (+ELU) for 16 nodes -> LDS -> GEMM2 -> h2 + elr2 ----
// Per node: out[h,f] = sum_e w[e,h]*h1[d_e,f] done as (16x32)x(32x32) MFMA:
//   A-frag = attention weights w (bf16), rows = heads (8 valid, 8 zero)
//   B-frag = gathered h1 rows (2 feat tiles of 16)
// Lane (q = lane>>4, m = lane&15): A[m][q*8+j], B[q*8+j][m].
__global__ __launch_bounds__(256)
void k_agg1g2(const unsigned short* __restrict__ h1b,
              const float* __restrict__ el1, const float* __restrict__ er1,
              const float* __restrict__ b1,
              const float* __restrict__ Wl2, const float* __restrict__ Wr2,
              const int* __restrict__ cnt, const unsigned short* __restrict__ csrp,
              const unsigned short* __restrict__ bp2,
              unsigned short* __restrict__ h2b,
              float* __restrict__ el2, float* __restrict__ er2){
    __shared__ __align__(16) unsigned short lds_r[16][264];
    __shared__ float lds_p[2][3][16];
    int w = threadIdx.x >> 6, lane = threadIdx.x & 63;
    int q = lane >> 4, m = lane & 15;
    int hm = m & 7;
    int base = blockIdx.x * 16;
    int node0 = base + w * 4;
    int4 n4 = *(const int4*)(cnt + node0);            // 16B-aligned
    int n_[4] = { min(n4.x, MAXDEG), min(n4.y, MAXDEG),
                  min(n4.z, MAXDEG), min(n4.w, MAXDEG) };
    float elh[4];
    #pragma unroll
    for (int i = 0; i < 4; i++) elh[i] = el1[(node0 + i)*8 + hm];
    float bv0 = b1[m], bv1 = b1[16 + m];
    #pragma unroll
    for (int i = 0; i < 4; i++){
        int n = n_[i];
        float el_h = elh[i];
        const unsigned short* lst = csrp + (size_t)(node0 + i) * MAXDEG;
        f32x4 acc0 = {0.f,0.f,0.f,0.f}, acc1 = {0.f,0.f,0.f,0.f};
        float dsum = 0.f;
        int nkb = (n + 31) >> 5;                      // 0, 1 or 2 K-blocks
        for (int kb = 0; kb < nkb; kb++){
            int s0 = kb*32 + q*8;
            // 8 edge ids in one 16B load (csrp rows are 16B-aligned)
            uint4 idp = *(const uint4*)(lst + s0);
            int idr[8];
            idr[0] = idp.x & 0xffff; idr[1] = idp.x >> 16;
            idr[2] = idp.y & 0xffff; idr[3] = idp.y >> 16;
            idr[4] = idp.z & 0xffff; idr[5] = idp.w >> 16; // fixed below
            idr[5] = idp.z >> 16;    idr[6] = idp.w & 0xffff;
            idr[7] = idp.w >> 16;
            #pragma unroll
            for (int j = 0; j < 8; j++) idr[j] = (idr[j] < N_NODES) ? idr[j] : 0;
            // attention weights for head m (rows 8..15 zero-padded)
            float wv[8];
            #pragma unroll
            for (int j = 0; j < 8; j++){
                float t = el_h + er1[idr[j]*8 + hm];
                t = (t > 0.f) ? t : 0.2f * t;
                float ev = __expf(fminf(t, 60.f));
                wv[j] = ((s0 + j) < n && m < 8) ? ev : 0.f;
            }
            dsum += ((wv[0]+wv[1])+(wv[2]+wv[3])) + ((wv[4]+wv[5])+(wv[6]+wv[7]));
            union { bf16x8 v; unsigned short s8[8]; } ua;
            #pragma unroll
            for (int j = 0; j < 8; j++) ua.s8[j] = f2b(wv[j]);
            // B-frags: feature m of 8 gathered rows, 2 tiles
            union { bf16x8 v; unsigned short s8[8]; } ub0, ub1;
            #pragma unroll
            for (int j = 0; j < 8; j++){
                const unsigned short* hr = h1b + (size_t)idr[j]*32;
                ub0.s8[j] = hr[m];
                ub1.s8[j] = hr[16 + m];
            }
            acc0 = __builtin_amdgcn_mfma_f32_16x16x32_bf16(ua.v, ub0.v, acc0, 0, 0, 0);
            acc1 = __builtin_amdgcn_mfma_f32_16x16x32_bf16(ua.v, ub1.v, acc1, 0, 0, 0);
        }
        dsum += __shfl_xor(dsum, 16);
        dsum += __shfl_xor(dsum, 32);                 // lane (.,m): denom of head m
        float inv = 1.f / fmaxf(dsum, 1e-12f);
        float ivr[4];
        #pragma unroll
        for (int r = 0; r < 4; r++) ivr[r] = __shfl(inv, 4*q + r);
        if (q < 2){                                   // C rows 0..7 = heads
            #pragma unroll
            for (int r = 0; r < 4; r++){
                int head = 4*q + r;
                float o0 = acc0[r]*ivr[r] + bv0;
                float o1 = acc1[r]*ivr[r] + bv1;
                o0 = (o0 > 0.f) ? o0 : (__expf(o0) - 1.f);
                o1 = (o1 > 0.f) ? o1 : (__expf(o1) - 1.f);
                lds_r[w*4 + i][head*32 + m]      = f2b(o0);
                lds_r[w*4 + i][head*32 + 16 + m] = f2b(o1);
            }
        }
    }
    __syncthreads();
    if (w < 3){
        f32x4 accd = {0.f,0.f,0.f,0.f};
        #pragma unroll
        for (int kc = 0; kc < 8; kc++){
            bf16x8 a = *reinterpret_cast<const bf16x8*>(&lds_r[m][kc*32 + q*8]);
            bf16x8 b = *reinterpret_cast<const bf16x8*>(bp2 + kc*1536 + w*512 + lane*8);
            accd = __builtin_amdgcn_mfma_f32_16x16x32_bf16(a, b, accd, 0, 0, 0);
        }
        int col = m, rbase = q * 4;
        int cls = w*16 + col;
        float wl2v = (cls < N_CLASS) ? Wl2[cls] : 0.f;
        float wr2v = (cls < N_CLASS) ? Wr2[cls] : 0.f;
        float pe[4], pr[4];
        #pragma unroll
        for (int r = 0; r < 4; r++){
            int grow = base + rbase + r;
            h2b[(size_t)grow*48 + w*16 + col] = f2b(accd[r]);
            pe[r] = accd[r] * wl2v;
            pr[r] = accd[r] * wr2v;
        }
        #pragma unroll
        for (int msk = 1; msk <= 8; msk <<= 1){
            #pragma unroll
            for (int r = 0; r < 4; r++){
                pe[r] += __shfl_xor(pe[r], msk);
                pr[r] += __shfl_xor(pr[r], msk);
            }
        }
        if (col == 0){
            #pragma unroll
            for (int r = 0; r < 4; r++){
                lds_p[0][w][rbase + r] = pe[r];
                lds_p[1][w][rbase + r] = pr[r];
            }
        }
    }
    __syncthreads();
    if (w == 3 && lane < 16){
        float ev = lds_p[0][0][lane] + lds_p[0][1][lane] + lds_p[0][2][lane];
        float rv = lds_p[1][0][lane] + lds_p[1][1][lane] + lds_p[1][2][lane];
        el2[base + lane] = ev;
        er2[base + lane] = rv;
    }
}

// ---- layer-2 aggregation + bias + log_softmax: wave per node, unroll x8 ----
__global__ __launch_bounds__(256)
void k_agg2(const unsigned short* __restrict__ h2b,
            const float* __restrict__ el2, const float* __restrict__ er2,
            const float* __restrict__ b2,
            const int* __restrict__ cnt, const unsigned short* __restrict__ csrp,
            float* __restrict__ out){
    int wid = (blockIdx.x * blockDim.x + threadIdx.x) >> 6;
    if (wid >= N_NODES) return;
    int lane = threadIdx.x & 63;
    int n = min(cnt[wid], MAXDEG);
    const unsigned short* lst = csrp + (size_t)wid * MAXDEG;
    float el_i = el2[wid];
    int   d_l = 0;
    float w_l = 0.f;
    if (lane < n){
        int dd = (int)lst[lane];
        d_l = (dd < N_NODES) ? dd : 0;
        float t = el_i + er2[d_l];
        t = (t > 0.f) ? t : 0.2f * t;
        w_l = __expf(fminf(t, 60.f));
    }
    float ds = w_l;
    #pragma unroll
    for (int m = 32; m >= 1; m >>= 1) ds += __shfl_xor(ds, m);
    bool valid = lane < N_CLASS;
    int cl = valid ? lane : 0;
    float acc0=0.f, acc1=0.f, acc2=0.f, acc3=0.f;
    for (int e = 0; e < n; e += 8){
        float we0 = __shfl(w_l, e);   int de0 = __shfl(d_l, e);
        float we1 = __shfl(w_l, e+1); int de1 = __shfl(d_l, e+1);
        float we2 = __shfl(w_l, e+2); int de2 = __shfl(d_l, e+2);
        float we3 = __shfl(w_l, e+3); int de3 = __shfl(d_l, e+3);
        float we4 = __shfl(w_l, e+4); int de4 = __shfl(d_l, e+4);
        float we5 = __shfl(w_l, e+5); int de5 = __shfl(d_l, e+5);
        float we6 = __shfl(w_l, e+6); int de6 = __shfl(d_l, e+6);
        float we7 = __shfl(w_l, e+7); int de7 = __shfl(d_l, e+7);
        acc0 += we0 * bf2f(h2b[(size_t)de0*48 + cl]);
        acc1 += we1 * bf2f(h2b[(size_t)de1*48 + cl]);
        acc2 += we2 * bf2f(h2b[(size_t)de2*48 + cl]);
        acc3 += we3 * bf2f(h2b[(size_t)de3*48 + cl]);
        acc0 += we4 * bf2f(h2b[(size_t)de4*48 + cl]);
        acc1 += we5 * bf2f(h2b[(size_t)de5*48 + cl]);
        acc2 += we6 * bf2f(h2b[(size_t)de6*48 + cl]);
        acc3 += we7 * bf2f(h2b[(size_t)de7*48 + cl]);
    }
    float acc = (acc0 + acc1) + (acc2 + acc3);
    float o = acc / fmaxf(ds, 1e-12f) + b2[cl];
    float zm = valid ? o : -1e30f;
    #pragma unroll
    for (int m = 32; m >= 1; m >>= 1) zm = fmaxf(zm, __shfl_xor(zm, m));
    float ex = valid ? __expf(fminf(o - zm, 0.f)) : 0.f;
    #pragma unroll
    for (int m = 32; m >= 1; m >>= 1) ex += __shfl_xor(ex, m);
    float res = o - zm - __logf(ex);
    if (valid) out[(size_t)wid*N_CLASS + lane] = res;
}

extern "C" void kernel_launch(void* const* d_in, const int* in_sizes, int n_in,
                              void* d_out, int out_size, void* d_ws, size_t ws_size,
                              hipStream_t stream){
    const float* x   = (const float*)d_in[0];
    const int*   esrc= (const int*)d_in[1];
    const int*   edst= (const int*)d_in[2];
    const float* W1  = (const float*)d_in[3];
    const float* Wl1 = (const float*)d_in[4];
    const float* Wr1 = (const float*)d_in[5];
    const float* b1  = (const float*)d_in[6];
    const float* W2  = (const float*)d_in[7];
    const float* Wl2 = (const float*)d_in[8];
    const float* Wr2 = (const float*)d_in[9];
    const float* b2  = (const float*)d_in[10];
    float* out = (float*)d_out;

    char* w = (char*)d_ws;
    auto carve = [&](size_t bytes) -> char* {
        char* p = w; w += (bytes + 255) & ~(size_t)255; return p;
    };
    int*            cnt  = (int*)            carve((size_t)N_NODES * 4);
    unsigned short* csrp = (unsigned short*) carve((size_t)N_NODES * MAXDEG * 2);
    unsigned short* h1b  = (unsigned short*) carve((size_t)N_NODES * 32 * 2);
    float*          el1  = (float*)          carve((size_t)N_NODES * 8 * 4);
    float*          er1  = (float*)          carve((size_t)N_NODES * 8 * 4);
    unsigned short* h2b  = (unsigned short*) carve((size_t)N_NODES * 48 * 2);
    float*          el2  = (float*)          carve((size_t)N_NODES * 4);
    float*          er2  = (float*)          carve((size_t)N_NODES * 4);
    unsigned short* bp1  = (unsigned short*) carve(8192 * 2);
    unsigned short* bp2  = (unsigned short*) carve(12288 * 2);
    unsigned short* bp3  = (unsigned short*) carve(512 * 2);

    k_pre    <<<(N_NODES + 255) / 256, 256, 0, stream>>>(W1, W2, Wl1, Wr1, cnt, bp1, bp2, bp3);
    k_fg     <<<G1BLK + (N_EDGES + 255) / 256, 256, 0, stream>>>(x, bp1, bp3, h1b, el1, er1,
                                                                 esrc, edst, cnt, csrp);
    k_agg1g2 <<<NW16, 256, 0, stream>>>(h1b, el1, er1, b1, Wl2, Wr2, cnt, csrp, bp2, h2b, el2, er2);
    k_agg2   <<<(N_NODES + 3) / 4, 256, 0, stream>>>(h2b, el2, er2, b2, cnt, csrp, out);
}